// Round 1
// baseline (1038.169 us; speedup 1.0000x reference)
//
#include <hip/hip_runtime.h>
#include <hip/hip_bf16.h>
#include <cmath>

#define CD 256
#define NQ 4096
#define NM 4096
#define NB 4
#define NTOT (NB*NQ)

typedef __bf16 bf16;
typedef __attribute__((ext_vector_type(8))) __bf16 bf16x8;
typedef __attribute__((ext_vector_type(4))) __bf16 bf16x4;
typedef __attribute__((ext_vector_type(4))) float f32x4;

#define MFMA(a,b,c) __builtin_amdgcn_mfma_f32_16x16x32_bf16(a,b,c,0,0,0)

// ---------------- K0: convert the four weight matrices to bf16 ----------------
__global__ __launch_bounds__(256) void cvt_w_kernel(
    const float* __restrict__ wq, const float* __restrict__ wk,
    const float* __restrict__ wv, const float* __restrict__ wm,
    bf16* __restrict__ out)
{
    int i = (blockIdx.x*256 + threadIdx.x)*4;   // 16384 threads * 4 elems = 65536
    const float* srcs[4] = {wq, wk, wv, wm};
    #pragma unroll
    for (int m=0;m<4;++m){
        f32x4 v = *(const f32x4*)(srcs[m]+i);
        bf16x4 o;
        #pragma unroll
        for (int e=0;e<4;++e) o[e] = (bf16)v[e];
        *(bf16x4*)(out + m*65536 + i) = o;
    }
}

// ---------------- K1: projection  out = X @ W^T + b  (bf16 out) ----------------
// MODE 0: out[n][co] bf16 row-major (q, k)
// MODE 1: out transposed per batch: vt[b][co][m] bf16 (v)
template<int MODE>
__global__ __launch_bounds__(256) void proj_kernel(
    const float* __restrict__ X, const bf16* __restrict__ W,
    const float* __restrict__ bias, bf16* __restrict__ out)
{
    const int wave = threadIdx.x>>6, lane = threadIdx.x&63;
    const int lr = lane&15, lg = lane>>4;
    const int n0 = blockIdx.x*64 + wave*16;

    // B-fragments of X (convert fp32->bf16 on the fly): x[n0+lr][ci=ch*32+lg*8+e]
    bf16x8 xf[8];
    {
        const float* xr = X + (size_t)(n0+lr)*CD + lg*8;
        #pragma unroll
        for (int ch=0; ch<8; ++ch){
            f32x4 a = *(const f32x4*)(xr + ch*32);
            f32x4 b = *(const f32x4*)(xr + ch*32 + 4);
            bf16x8 t;
            #pragma unroll
            for (int e=0;e<4;++e){ t[e]=(bf16)a[e]; t[4+e]=(bf16)b[e]; }
            xf[ch]=t;
        }
    }
    f32x4 acc[16];
    #pragma unroll
    for (int t=0;t<16;++t) acc[t]=(f32x4){0,0,0,0};

    #pragma unroll
    for (int t=0;t<16;++t){
        const bf16* wr = W + (size_t)(t*16+lr)*CD + lg*8;
        #pragma unroll
        for (int ch=0; ch<8; ++ch){
            bf16x8 wf = *(const bf16x8*)(wr + ch*32);
            if (MODE==0) acc[t] = MFMA(wf, xf[ch], acc[t]);   // D[co, n]
            else         acc[t] = MFMA(xf[ch], wf, acc[t]);   // D[n, co]
        }
    }

    if (MODE==0){
        // D: col(lane&15)=n, row(4*lg+r)=co  -> 4 consecutive co per lane
        const int n = n0 + lr;
        #pragma unroll
        for (int t=0;t<16;++t){
            int co = t*16 + 4*lg;
            bf16x4 o;
            #pragma unroll
            for (int r=0;r<4;++r) o[r] = (bf16)(acc[t][r] + bias[co+r]);
            *(bf16x4*)(out + (size_t)n*CD + co) = o;
        }
    } else {
        // D: col(lane&15)=co, row(4*lg+r)=n -> 4 consecutive n, store transposed
        const int b = n0 / NM;
        const int m0 = (n0 % NM) + 4*lg;
        #pragma unroll
        for (int t=0;t<16;++t){
            int co = t*16 + lr;
            float bb = bias[co];
            bf16x4 o;
            #pragma unroll
            for (int r=0;r<4;++r) o[r] = (bf16)(acc[t][r] + bb);
            *(bf16x4*)(out + (size_t)b*CD*NM + (size_t)co*NM + m0) = o;
        }
    }
}

// ---------------- K2: pass 1 — per-row max / rstd of S = q k^T ----------------
__global__ __launch_bounds__(256) void stats_kernel(
    const bf16* __restrict__ q, const bf16* __restrict__ k,
    float* __restrict__ stats)                 // [NTOT][2] = {mx, a2}
{
    const int wave = threadIdx.x>>6, lane = threadIdx.x&63;
    const int lr = lane&15, lg = lane>>4;
    const int n0 = blockIdx.x*64 + wave*16;
    const int b = n0 / NQ;
    const bf16* kb = k + (size_t)b*NM*CD;

    bf16x8 qf[8];
    const bf16* qr = q + (size_t)(n0+lr)*CD + lg*8;
    #pragma unroll
    for (int ch=0; ch<8; ++ch) qf[ch] = *(const bf16x8*)(qr + ch*32);

    float sum[4]={0,0,0,0}, ssq[4]={0,0,0,0}, mx[4];
    #pragma unroll
    for (int r=0;r<4;++r) mx[r] = -3.0e38f;

    for (int j0=0; j0<NM; j0+=16){
        f32x4 acc = (f32x4){0,0,0,0};
        const bf16* kr = kb + (size_t)(j0+lr)*CD + lg*8;
        #pragma unroll
        for (int ch=0; ch<8; ++ch)
            acc = MFMA(qf[ch], *(const bf16x8*)(kr + ch*32), acc);
        #pragma unroll
        for (int r=0;r<4;++r){
            float s = acc[r];
            sum[r] += s; ssq[r] = fmaf(s,s,ssq[r]); mx[r] = fmaxf(mx[r], s);
        }
    }
    // reduce over the 16 j-columns held across lanes (lane&15)
    #pragma unroll
    for (int off=1; off<16; off<<=1){
        #pragma unroll
        for (int r=0;r<4;++r){
            sum[r] += __shfl_xor(sum[r], off);
            ssq[r] += __shfl_xor(ssq[r], off);
            mx[r]  = fmaxf(mx[r], __shfl_xor(mx[r], off));
        }
    }
    if (lr==0){
        #pragma unroll
        for (int r=0;r<4;++r){
            int row = n0 + 4*lg + r;
            float mean = sum[r] * (1.0f/NM);
            float var  = ssq[r] * (1.0f/NM) - mean*mean;
            float rstd = rsqrtf(fmaxf(var,0.0f) + 1e-5f);
            stats[row*2+0] = mx[r];
            stats[row*2+1] = rstd * (1.0f/16.0f) * 1.4426950408889634f; // a2 (log2-domain)
        }
    }
}

// ---------------- K3: pass 2 — recompute S, softmax, PV, residual ----------------
__global__ __launch_bounds__(256) void flash_kernel(
    const bf16* __restrict__ q, const bf16* __restrict__ k,
    const bf16* __restrict__ vt, const float* __restrict__ stats,
    const float* __restrict__ query, bf16* __restrict__ u)
{
    __shared__ __align__(16) bf16 plds[4][16][40];   // per-wave P tile, padded stride 80B
    const int wave = threadIdx.x>>6, lane = threadIdx.x&63;
    const int lr = lane&15, lg = lane>>4;
    const int n0 = blockIdx.x*64 + wave*16;
    const int b = n0 / NQ;
    const bf16* kb = k  + (size_t)b*NM*CD;
    const bf16* vb = vt + (size_t)b*CD*NM;

    bf16x8 qf[8];
    const bf16* qr = q + (size_t)(n0+lr)*CD + lg*8;
    #pragma unroll
    for (int ch=0; ch<8; ++ch) qf[ch] = *(const bf16x8*)(qr + ch*32);

    float mxr[4], a2r[4];
    #pragma unroll
    for (int r=0;r<4;++r){
        int row = n0 + 4*lg + r;
        mxr[r] = stats[row*2+0];
        a2r[r] = stats[row*2+1];
    }

    f32x4 oacc[16];
    #pragma unroll
    for (int t=0;t<16;++t) oacc[t]=(f32x4){0,0,0,0};
    float denom[4]={0,0,0,0};

    for (int j0=0; j0<NM; j0+=32){
        #pragma unroll
        for (int half=0; half<2; ++half){
            f32x4 acc=(f32x4){0,0,0,0};
            const bf16* kr = kb + (size_t)(j0+half*16+lr)*CD + lg*8;
            #pragma unroll
            for (int ch=0; ch<8; ++ch)
                acc = MFMA(qf[ch], *(const bf16x8*)(kr+ch*32), acc);
            #pragma unroll
            for (int r=0;r<4;++r){
                float p = exp2f((acc[r]-mxr[r])*a2r[r]);  // <= 1
                denom[r] += p;
                plds[wave][4*lg+r][half*16+lr] = (bf16)p;
            }
        }
        __syncthreads();
        bf16x8 pf = *(const bf16x8*)&plds[wave][lr][lg*8];  // A-frag: P[row=lr][j=lg*8+e]
        #pragma unroll
        for (int t=0;t<16;++t){
            const bf16* vr = vb + (size_t)(t*16+lr)*NM + j0 + lg*8;
            oacc[t] = MFMA(pf, *(const bf16x8*)vr, oacc[t]);
        }
        __syncthreads();
    }

    // full row denom: reduce partial sums over lane&15
    #pragma unroll
    for (int off=1; off<16; off<<=1){
        #pragma unroll
        for (int r=0;r<4;++r) denom[r] += __shfl_xor(denom[r], off);
    }
    float dinv[4];
    #pragma unroll
    for (int r=0;r<4;++r) dinv[r] = 1.0f/denom[r];

    // u = query + O/denom   (D: row=4lg+r -> q row, col=t*16+lr -> c)
    #pragma unroll
    for (int t=0;t<16;++t){
        #pragma unroll
        for (int r=0;r<4;++r){
            int row = n0 + 4*lg + r;
            int c = t*16 + lr;
            float val = query[(size_t)row*CD + c] + oacc[t][r]*dinv[r];
            u[(size_t)row*CD + c] = (bf16)val;
        }
    }
}

// ---------------- K4: final projection  out = u @ Wm^T + bm  (fp32 out) ----------------
__global__ __launch_bounds__(256) void final_kernel(
    const bf16* __restrict__ U, const bf16* __restrict__ W,
    const float* __restrict__ bias, float* __restrict__ out)
{
    const int wave = threadIdx.x>>6, lane = threadIdx.x&63;
    const int lr = lane&15, lg = lane>>4;
    const int n0 = blockIdx.x*64 + wave*16;

    bf16x8 uf[8];
    const bf16* ur = U + (size_t)(n0+lr)*CD + lg*8;
    #pragma unroll
    for (int ch=0; ch<8; ++ch) uf[ch] = *(const bf16x8*)(ur + ch*32);

    f32x4 acc[16];
    #pragma unroll
    for (int t=0;t<16;++t) acc[t]=(f32x4){0,0,0,0};

    #pragma unroll
    for (int t=0;t<16;++t){
        const bf16* wr = W + (size_t)(t*16+lr)*CD + lg*8;
        #pragma unroll
        for (int ch=0; ch<8; ++ch)
            acc[t] = MFMA(*(const bf16x8*)(wr+ch*32), uf[ch], acc[t]);
    }
    const int n = n0 + lr;
    #pragma unroll
    for (int t=0;t<16;++t){
        int co = t*16 + 4*lg;
        f32x4 o;
        #pragma unroll
        for (int r=0;r<4;++r) o[r] = acc[t][r] + bias[co+r];
        *(f32x4*)(out + (size_t)n*CD + co) = o;
    }
}

extern "C" void kernel_launch(void* const* d_in, const int* in_sizes, int n_in,
                              void* d_out, int out_size, void* d_ws, size_t ws_size,
                              hipStream_t stream)
{
    const float* query = (const float*)d_in[0];
    const float* key_  = (const float*)d_in[1];
    const float* value = (const float*)d_in[2];
    const float* Wq = (const float*)d_in[3];
    const float* bq = (const float*)d_in[4];
    const float* Wk = (const float*)d_in[5];
    const float* bk = (const float*)d_in[6];
    const float* Wv = (const float*)d_in[7];
    const float* bv = (const float*)d_in[8];
    const float* Wm = (const float*)d_in[9];
    const float* bm = (const float*)d_in[10];
    float* out = (float*)d_out;

    bf16* wsb = (bf16*)d_ws;
    bf16* wqb = wsb;                      // 4 x 65536 bf16 weights
    bf16* wkb = wqb + 65536;
    bf16* wvb = wkb + 65536;
    bf16* wmb = wvb + 65536;
    bf16* qbuf  = wsb + 4*65536;          // [NTOT][256] bf16
    bf16* kbuf  = qbuf  + (size_t)NTOT*CD;
    bf16* vtbuf = kbuf  + (size_t)NTOT*CD;   // [B][256][NM] bf16 (transposed V)
    bf16* ubuf  = vtbuf + (size_t)NTOT*CD;   // [NTOT][256] bf16 residual+attn
    float* statsbuf = (float*)(ubuf + (size_t)NTOT*CD);  // [NTOT][2]

    cvt_w_kernel<<<64,256,0,stream>>>(Wq, Wk, Wv, Wm, wsb);
    proj_kernel<0><<<256,256,0,stream>>>(query, wqb, bq, qbuf);
    proj_kernel<0><<<256,256,0,stream>>>(key_,  wkb, bk, kbuf);
    proj_kernel<1><<<256,256,0,stream>>>(value, wvb, bv, vtbuf);
    stats_kernel<<<256,256,0,stream>>>(qbuf, kbuf, statsbuf);
    flash_kernel<<<256,256,0,stream>>>(qbuf, kbuf, vtbuf, statsbuf, query, ubuf);
    final_kernel<<<256,256,0,stream>>>(ubuf, wmb, bm, out);
}

// Round 6
// 870.638 us; speedup vs baseline: 1.1924x; 1.1924x over previous
//
#include <hip/hip_runtime.h>
#include <hip/hip_bf16.h>
#include <cmath>

#define CD 256
#define NQ 4096
#define NM 4096
#define NB 4
#define NTOT (NB*NQ)

typedef __bf16 bf16;
typedef __attribute__((ext_vector_type(8))) __bf16 bf16x8;
typedef __attribute__((ext_vector_type(4))) __bf16 bf16x4;
typedef __attribute__((ext_vector_type(4))) float f32x4;

#define MFMA(a,b,c) __builtin_amdgcn_mfma_f32_16x16x32_bf16(a,b,c,0,0,0)

// ---------------- K0: convert the four weight matrices to bf16 ----------------
__global__ __launch_bounds__(256) void cvt_w_kernel(
    const float* __restrict__ wq, const float* __restrict__ wk,
    const float* __restrict__ wv, const float* __restrict__ wm,
    bf16* __restrict__ out)
{
    int i = (blockIdx.x*256 + threadIdx.x)*4;
    const float* srcs[4] = {wq, wk, wv, wm};
    #pragma unroll
    for (int m=0;m<4;++m){
        f32x4 v = *(const f32x4*)(srcs[m]+i);
        bf16x4 o;
        #pragma unroll
        for (int e=0;e<4;++e) o[e] = (bf16)v[e];
        *(bf16x4*)(out + m*65536 + i) = o;
    }
}

// ---------------- K1: projection  out = X @ W^T + b  (bf16 out) ----------------
// co-split 2: blockIdx.x = rowblk*2 + cohalf (GRID MUST BE 512).
// MODE 0: out[n][co] bf16 row-major (q, k)
// MODE 1: out transposed per batch: vt[b][co][m] bf16 (v)
template<int MODE>
__global__ __launch_bounds__(256) void proj_kernel(
    const float* __restrict__ X, const bf16* __restrict__ W,
    const float* __restrict__ bias, bf16* __restrict__ out)
{
    const int wave = threadIdx.x>>6, lane = threadIdx.x&63;
    const int lr = lane&15, lg = lane>>4;
    const int n0 = (blockIdx.x>>1)*64 + wave*16;
    const int co0 = (blockIdx.x&1)*128;

    bf16x8 xf[8];
    {
        const float* xr = X + (size_t)(n0+lr)*CD + lg*8;
        #pragma unroll
        for (int ch=0; ch<8; ++ch){
            f32x4 a = *(const f32x4*)(xr + ch*32);
            f32x4 b = *(const f32x4*)(xr + ch*32 + 4);
            bf16x8 t;
            #pragma unroll
            for (int e=0;e<4;++e){ t[e]=(bf16)a[e]; t[4+e]=(bf16)b[e]; }
            xf[ch]=t;
        }
    }
    f32x4 acc[8];
    #pragma unroll
    for (int t=0;t<8;++t) acc[t]=(f32x4){0,0,0,0};

    #pragma unroll
    for (int t=0;t<8;++t){
        const bf16* wr = W + (size_t)(co0+t*16+lr)*CD + lg*8;
        #pragma unroll
        for (int ch=0; ch<8; ++ch){
            bf16x8 wf = *(const bf16x8*)(wr + ch*32);
            if (MODE==0) acc[t] = MFMA(wf, xf[ch], acc[t]);   // D[co, n]
            else         acc[t] = MFMA(xf[ch], wf, acc[t]);   // D[n, co]
        }
    }

    if (MODE==0){
        const int n = n0 + lr;
        #pragma unroll
        for (int t=0;t<8;++t){
            int co = co0 + t*16 + 4*lg;
            bf16x4 o;
            #pragma unroll
            for (int r=0;r<4;++r) o[r] = (bf16)(acc[t][r] + bias[co+r]);
            *(bf16x4*)(out + (size_t)n*CD + co) = o;
        }
    } else {
        const int b = n0 / NM;
        const int m0 = (n0 % NM) + 4*lg;
        #pragma unroll
        for (int t=0;t<8;++t){
            int co = co0 + t*16 + lr;
            float bb = bias[co];
            bf16x4 o;
            #pragma unroll
            for (int r=0;r<4;++r) o[r] = (bf16)(acc[t][r] + bb);
            *(bf16x4*)(out + (size_t)b*CD*NM + (size_t)co*NM + m0) = o;
        }
    }
}

// ---------------- K2: pass 1 — per-row max / rstd of S = q k^T ----------------
// Block: 4 waves share one 16-row q tile; wave w covers j in [w*NM/4,(w+1)*NM/4).
__global__ __launch_bounds__(256) void stats_kernel(
    const bf16* __restrict__ q, const bf16* __restrict__ k,
    float* __restrict__ stats)                 // [NTOT][2] = {mx, a2}
{
    __shared__ float sbuf[3][4][16];
    const int wave = threadIdx.x>>6, lane = threadIdx.x&63;
    const int lr = lane&15, lg = lane>>4;
    const int n0 = blockIdx.x*16;
    const int b = n0 / NQ;
    const bf16* kb = k + (size_t)b*NM*CD;

    bf16x8 qf[8];
    const bf16* qr = q + (size_t)(n0+lr)*CD + lg*8;
    #pragma unroll
    for (int ch=0; ch<8; ++ch) qf[ch] = *(const bf16x8*)(qr + ch*32);

    float sum[4]={0,0,0,0}, ssq[4]={0,0,0,0}, mx[4];
    #pragma unroll
    for (int r=0;r<4;++r) mx[r] = -3.0e38f;

    const int jbeg = wave*(NM/4), jend = jbeg + NM/4;
    for (int j0=jbeg; j0<jend; j0+=32){
        f32x4 acc0 = (f32x4){0,0,0,0};
        f32x4 acc1 = (f32x4){0,0,0,0};
        const bf16* kr0 = kb + (size_t)(j0+lr)*CD + lg*8;
        const bf16* kr1 = kr0 + 16*CD;
        #pragma unroll
        for (int ch=0; ch<8; ++ch){
            acc0 = MFMA(qf[ch], *(const bf16x8*)(kr0 + ch*32), acc0);
            acc1 = MFMA(qf[ch], *(const bf16x8*)(kr1 + ch*32), acc1);
        }
        #pragma unroll
        for (int r=0;r<4;++r){
            float s0 = acc0[r], s1 = acc1[r];
            sum[r] += s0 + s1;
            ssq[r] = fmaf(s0,s0,ssq[r]); ssq[r] = fmaf(s1,s1,ssq[r]);
            mx[r] = fmaxf(mx[r], fmaxf(s0, s1));
        }
    }
    #pragma unroll
    for (int off=1; off<16; off<<=1){
        #pragma unroll
        for (int r=0;r<4;++r){
            sum[r] += __shfl_xor(sum[r], off);
            ssq[r] += __shfl_xor(ssq[r], off);
            mx[r]  = fmaxf(mx[r], __shfl_xor(mx[r], off));
        }
    }
    if (lr==0){
        #pragma unroll
        for (int r=0;r<4;++r){
            sbuf[0][wave][4*lg+r] = sum[r];
            sbuf[1][wave][4*lg+r] = ssq[r];
            sbuf[2][wave][4*lg+r] = mx[r];
        }
    }
    __syncthreads();
    if (wave==0 && lane<16){
        float S=0, Q=0, M=-3.0e38f;
        #pragma unroll
        for (int w=0;w<4;++w){
            S += sbuf[0][w][lane];
            Q += sbuf[1][w][lane];
            M  = fmaxf(M, sbuf[2][w][lane]);
        }
        float mean = S * (1.0f/NM);
        float var  = Q * (1.0f/NM) - mean*mean;
        float rstd = rsqrtf(fmaxf(var,0.0f) + 1e-5f);
        int row = n0 + lane;
        stats[row*2+0] = M;
        stats[row*2+1] = rstd * (1.0f/16.0f) * 1.4426950408889634f;
    }
}

// ---------------- K3: pass 2 — recompute S, softmax, PV, residual ----------------
// Block: 4 waves share one 16-row q tile; wave w covers j in [w*NM/4,(w+1)*NM/4).
// Partials combined in-block via LDS.
__global__ __launch_bounds__(256) void flash_kernel(
    const bf16* __restrict__ q, const bf16* __restrict__ k,
    const bf16* __restrict__ vt, const float* __restrict__ stats,
    const float* __restrict__ query, bf16* __restrict__ u)
{
    __shared__ __align__(16) float obuf[16][260];   // combine buffer, padded
    __shared__ float dbuf[4][16];
    __shared__ __align__(16) bf16 plds[4][16][40];  // per-wave P tile
    const int wave = threadIdx.x>>6, lane = threadIdx.x&63;
    const int lr = lane&15, lg = lane>>4;
    const int n0 = blockIdx.x*16;
    const int b = n0 / NQ;
    const bf16* kb = k  + (size_t)b*NM*CD;
    const bf16* vb = vt + (size_t)b*CD*NM;

    bf16x8 qf[8];
    const bf16* qr = q + (size_t)(n0+lr)*CD + lg*8;
    #pragma unroll
    for (int ch=0; ch<8; ++ch) qf[ch] = *(const bf16x8*)(qr + ch*32);

    float mxr[4], a2r[4];
    #pragma unroll
    for (int r=0;r<4;++r){
        int row = n0 + 4*lg + r;
        mxr[r] = stats[row*2+0];
        a2r[r] = stats[row*2+1];
    }

    f32x4 oacc[16];
    #pragma unroll
    for (int t=0;t<16;++t) oacc[t]=(f32x4){0,0,0,0};
    float denom[4]={0,0,0,0};

    const int jbeg = wave*(NM/4), jend = jbeg + NM/4;
    for (int j0=jbeg; j0<jend; j0+=32){
        f32x4 acc0=(f32x4){0,0,0,0};
        f32x4 acc1=(f32x4){0,0,0,0};
        const bf16* kr0 = kb + (size_t)(j0+lr)*CD + lg*8;
        const bf16* kr1 = kr0 + 16*CD;
        #pragma unroll
        for (int ch=0; ch<8; ++ch){
            acc0 = MFMA(qf[ch], *(const bf16x8*)(kr0+ch*32), acc0);
            acc1 = MFMA(qf[ch], *(const bf16x8*)(kr1+ch*32), acc1);
        }
        #pragma unroll
        for (int r=0;r<4;++r){
            float p0 = exp2f((acc0[r]-mxr[r])*a2r[r]);
            float p1 = exp2f((acc1[r]-mxr[r])*a2r[r]);
            denom[r] += p0 + p1;
            plds[wave][4*lg+r][lr]    = (bf16)p0;
            plds[wave][4*lg+r][16+lr] = (bf16)p1;
        }
        // per-wave LDS tile: wave-internal ordering only (compiler inserts lgkmcnt)
        bf16x8 pf = *(const bf16x8*)&plds[wave][lr][lg*8];
        #pragma unroll
        for (int t=0;t<16;++t){
            const bf16* vr = vb + (size_t)(t*16+lr)*NM + j0 + lg*8;
            oacc[t] = MFMA(pf, *(const bf16x8*)vr, oacc[t]);
        }
    }

    // partial denom: reduce over lane&15 within wave
    #pragma unroll
    for (int off=1; off<16; off<<=1){
        #pragma unroll
        for (int r=0;r<4;++r) denom[r] += __shfl_xor(denom[r], off);
    }
    if (lr==0){
        #pragma unroll
        for (int r=0;r<4;++r) dbuf[wave][4*lg+r] = denom[r];
    }

    // combine oacc across waves (serialized adds into obuf)
    __syncthreads();
    if (wave==0){
        #pragma unroll
        for (int t=0;t<16;++t)
            #pragma unroll
            for (int r=0;r<4;++r) obuf[4*lg+r][t*16+lr] = oacc[t][r];
    }
    __syncthreads();
    if (wave==1){
        #pragma unroll
        for (int t=0;t<16;++t)
            #pragma unroll
            for (int r=0;r<4;++r) obuf[4*lg+r][t*16+lr] += oacc[t][r];
    }
    __syncthreads();
    if (wave==2){
        #pragma unroll
        for (int t=0;t<16;++t)
            #pragma unroll
            for (int r=0;r<4;++r) obuf[4*lg+r][t*16+lr] += oacc[t][r];
    }
    __syncthreads();
    if (wave==3){
        #pragma unroll
        for (int t=0;t<16;++t)
            #pragma unroll
            for (int r=0;r<4;++r) obuf[4*lg+r][t*16+lr] += oacc[t][r];
    }
    __syncthreads();

    // final: each wave writes a quarter of the columns
    float dall[4];
    #pragma unroll
    for (int r=0;r<4;++r){
        int i = 4*lg + r;
        dall[r] = 1.0f / (dbuf[0][i] + dbuf[1][i] + dbuf[2][i] + dbuf[3][i]);
    }
    #pragma unroll
    for (int tt=0;tt<4;++tt){
        int t = wave*4 + tt;
        #pragma unroll
        for (int r=0;r<4;++r){
            int row = n0 + 4*lg + r;
            int c = t*16 + lr;
            float val = query[(size_t)row*CD + c] + obuf[4*lg+r][c] * dall[r];
            u[(size_t)row*CD + c] = (bf16)val;
        }
    }
}

// ---------------- K4: final projection  out = u @ Wm^T + bm  (fp32 out) ----------------
// GRID MUST BE 512 (blockIdx.x = rowblk*2 + cohalf).
__global__ __launch_bounds__(256) void final_kernel(
    const bf16* __restrict__ U, const bf16* __restrict__ W,
    const float* __restrict__ bias, float* __restrict__ out)
{
    const int wave = threadIdx.x>>6, lane = threadIdx.x&63;
    const int lr = lane&15, lg = lane>>4;
    const int n0 = (blockIdx.x>>1)*64 + wave*16;
    const int co0 = (blockIdx.x&1)*128;

    bf16x8 uf[8];
    const bf16* ur = U + (size_t)(n0+lr)*CD + lg*8;
    #pragma unroll
    for (int ch=0; ch<8; ++ch) uf[ch] = *(const bf16x8*)(ur + ch*32);

    f32x4 acc[8];
    #pragma unroll
    for (int t=0;t<8;++t) acc[t]=(f32x4){0,0,0,0};

    #pragma unroll
    for (int t=0;t<8;++t){
        const bf16* wr = W + (size_t)(co0+t*16+lr)*CD + lg*8;
        #pragma unroll
        for (int ch=0; ch<8; ++ch)
            acc[t] = MFMA(*(const bf16x8*)(wr+ch*32), uf[ch], acc[t]);
    }
    const int n = n0 + lr;
    #pragma unroll
    for (int t=0;t<8;++t){
        int co = co0 + t*16 + 4*lg;
        f32x4 o;
        #pragma unroll
        for (int r=0;r<4;++r) o[r] = acc[t][r] + bias[co+r];
        *(f32x4*)(out + (size_t)n*CD + co) = o;
    }
}

extern "C" void kernel_launch(void* const* d_in, const int* in_sizes, int n_in,
                              void* d_out, int out_size, void* d_ws, size_t ws_size,
                              hipStream_t stream)
{
    const float* query = (const float*)d_in[0];
    const float* key_  = (const float*)d_in[1];
    const float* value = (const float*)d_in[2];
    const float* Wq = (const float*)d_in[3];
    const float* bq = (const float*)d_in[4];
    const float* Wk = (const float*)d_in[5];
    const float* bk = (const float*)d_in[6];
    const float* Wv = (const float*)d_in[7];
    const float* bv = (const float*)d_in[8];
    const float* Wm = (const float*)d_in[9];
    const float* bm = (const float*)d_in[10];
    float* out = (float*)d_out;

    bf16* wsb = (bf16*)d_ws;
    bf16* wqb = wsb;
    bf16* wkb = wqb + 65536;
    bf16* wvb = wkb + 65536;
    bf16* wmb = wvb + 65536;
    bf16* qbuf  = wsb + 4*65536;
    bf16* kbuf  = qbuf  + (size_t)NTOT*CD;
    bf16* vtbuf = kbuf  + (size_t)NTOT*CD;
    bf16* ubuf  = vtbuf + (size_t)NTOT*CD;
    float* statsbuf = (float*)(ubuf + (size_t)NTOT*CD);

    cvt_w_kernel<<<64,256,0,stream>>>(Wq, Wk, Wv, Wm, wsb);
    proj_kernel<0><<<512,256,0,stream>>>(query, wqb, bq, qbuf);
    proj_kernel<0><<<512,256,0,stream>>>(key_,  wkb, bk, kbuf);
    proj_kernel<1><<<512,256,0,stream>>>(value, wvb, bv, vtbuf);
    stats_kernel<<<1024,256,0,stream>>>(qbuf, kbuf, statsbuf);
    flash_kernel<<<1024,256,0,stream>>>(qbuf, kbuf, vtbuf, statsbuf, query, ubuf);
    final_kernel<<<512,256,0,stream>>>(ubuf, wmb, bm, out);   // grid 512 — NOT 1024 (R2-R4 fault)
}

// Round 7
// 865.123 us; speedup vs baseline: 1.2000x; 1.0064x over previous
//
#include <hip/hip_runtime.h>
#include <hip/hip_bf16.h>
#include <cmath>

#define CD 256
#define NQ 4096
#define NM 4096
#define NB 4
#define NTOT (NB*NQ)

typedef __bf16 bf16;
typedef __attribute__((ext_vector_type(8))) __bf16 bf16x8;
typedef __attribute__((ext_vector_type(4))) __bf16 bf16x4;
typedef __attribute__((ext_vector_type(4))) float f32x4;

#define MFMA(a,b,c) __builtin_amdgcn_mfma_f32_16x16x32_bf16(a,b,c,0,0,0)

// ---------------- K0: convert the four weight matrices to bf16 ----------------
__global__ __launch_bounds__(256) void cvt_w_kernel(
    const float* __restrict__ wq, const float* __restrict__ wk,
    const float* __restrict__ wv, const float* __restrict__ wm,
    bf16* __restrict__ out)
{
    int i = (blockIdx.x*256 + threadIdx.x)*4;
    const float* srcs[4] = {wq, wk, wv, wm};
    #pragma unroll
    for (int m=0;m<4;++m){
        f32x4 v = *(const f32x4*)(srcs[m]+i);
        bf16x4 o;
        #pragma unroll
        for (int e=0;e<4;++e) o[e] = (bf16)v[e];
        *(bf16x4*)(out + m*65536 + i) = o;
    }
}

// ---------------- K1: projection  out = X @ W^T + b  (bf16 out) ----------------
// co-split 2: blockIdx.x = rowblk*2 + cohalf (GRID MUST BE 512).
template<int MODE>
__global__ __launch_bounds__(256) void proj_kernel(
    const float* __restrict__ X, const bf16* __restrict__ W,
    const float* __restrict__ bias, bf16* __restrict__ out)
{
    const int wave = threadIdx.x>>6, lane = threadIdx.x&63;
    const int lr = lane&15, lg = lane>>4;
    const int n0 = (blockIdx.x>>1)*64 + wave*16;
    const int co0 = (blockIdx.x&1)*128;

    bf16x8 xf[8];
    {
        const float* xr = X + (size_t)(n0+lr)*CD + lg*8;
        #pragma unroll
        for (int ch=0; ch<8; ++ch){
            f32x4 a = *(const f32x4*)(xr + ch*32);
            f32x4 b = *(const f32x4*)(xr + ch*32 + 4);
            bf16x8 t;
            #pragma unroll
            for (int e=0;e<4;++e){ t[e]=(bf16)a[e]; t[4+e]=(bf16)b[e]; }
            xf[ch]=t;
        }
    }
    f32x4 acc[8];
    #pragma unroll
    for (int t=0;t<8;++t) acc[t]=(f32x4){0,0,0,0};

    #pragma unroll
    for (int t=0;t<8;++t){
        const bf16* wr = W + (size_t)(co0+t*16+lr)*CD + lg*8;
        #pragma unroll
        for (int ch=0; ch<8; ++ch){
            bf16x8 wf = *(const bf16x8*)(wr + ch*32);
            if (MODE==0) acc[t] = MFMA(wf, xf[ch], acc[t]);   // D[co, n]
            else         acc[t] = MFMA(xf[ch], wf, acc[t]);   // D[n, co]
        }
    }

    if (MODE==0){
        const int n = n0 + lr;
        #pragma unroll
        for (int t=0;t<8;++t){
            int co = co0 + t*16 + 4*lg;
            bf16x4 o;
            #pragma unroll
            for (int r=0;r<4;++r) o[r] = (bf16)(acc[t][r] + bias[co+r]);
            *(bf16x4*)(out + (size_t)n*CD + co) = o;
        }
    } else {
        const int b = n0 / NM;
        const int m0 = (n0 % NM) + 4*lg;
        #pragma unroll
        for (int t=0;t<8;++t){
            int co = co0 + t*16 + lr;
            float bb = bias[co];
            bf16x4 o;
            #pragma unroll
            for (int r=0;r<4;++r) o[r] = (bf16)(acc[t][r] + bb);
            *(bf16x4*)(out + (size_t)b*CD*NM + (size_t)co*NM + m0) = o;
        }
    }
}

// ---------------- K2: pass 1 — per-row max / rstd of S = q k^T ----------------
// 4 waves share one 16-row q tile; wave w covers j quarter. 4-chain split-K ILP.
__global__ __launch_bounds__(256) void stats_kernel(
    const bf16* __restrict__ q, const bf16* __restrict__ k,
    float* __restrict__ stats)                 // [NTOT][2] = {mx, a2}
{
    __shared__ float sbuf[3][4][16];
    const int wave = threadIdx.x>>6, lane = threadIdx.x&63;
    const int lr = lane&15, lg = lane>>4;
    const int n0 = blockIdx.x*16;
    const int b = n0 / NQ;
    const bf16* kb = k + (size_t)b*NM*CD;

    bf16x8 qf[8];
    const bf16* qr = q + (size_t)(n0+lr)*CD + lg*8;
    #pragma unroll
    for (int ch=0; ch<8; ++ch) qf[ch] = *(const bf16x8*)(qr + ch*32);

    float sum[4]={0,0,0,0}, ssq[4]={0,0,0,0}, mx[4];
    #pragma unroll
    for (int r=0;r<4;++r) mx[r] = -3.0e38f;

    const int jbeg = wave*(NM/4), jend = jbeg + NM/4;
    for (int j0=jbeg; j0<jend; j0+=32){
        // 4 independent MFMA chains (2 j-subtiles x split-K halves)
        f32x4 a00=(f32x4){0,0,0,0}, a01=(f32x4){0,0,0,0};
        f32x4 a10=(f32x4){0,0,0,0}, a11=(f32x4){0,0,0,0};
        const bf16* kr0 = kb + (size_t)(j0+lr)*CD + lg*8;
        const bf16* kr1 = kr0 + 16*CD;
        #pragma unroll
        for (int ch=0; ch<4; ++ch){
            a00 = MFMA(qf[ch],   *(const bf16x8*)(kr0 + ch*32),     a00);
            a10 = MFMA(qf[ch],   *(const bf16x8*)(kr1 + ch*32),     a10);
            a01 = MFMA(qf[ch+4], *(const bf16x8*)(kr0 + (ch+4)*32), a01);
            a11 = MFMA(qf[ch+4], *(const bf16x8*)(kr1 + (ch+4)*32), a11);
        }
        #pragma unroll
        for (int r=0;r<4;++r){
            float s0 = a00[r]+a01[r], s1 = a10[r]+a11[r];
            sum[r] += s0 + s1;
            ssq[r] = fmaf(s0,s0,ssq[r]); ssq[r] = fmaf(s1,s1,ssq[r]);
            mx[r] = fmaxf(mx[r], fmaxf(s0, s1));
        }
    }
    #pragma unroll
    for (int off=1; off<16; off<<=1){
        #pragma unroll
        for (int r=0;r<4;++r){
            sum[r] += __shfl_xor(sum[r], off);
            ssq[r] += __shfl_xor(ssq[r], off);
            mx[r]  = fmaxf(mx[r], __shfl_xor(mx[r], off));
        }
    }
    if (lr==0){
        #pragma unroll
        for (int r=0;r<4;++r){
            sbuf[0][wave][4*lg+r] = sum[r];
            sbuf[1][wave][4*lg+r] = ssq[r];
            sbuf[2][wave][4*lg+r] = mx[r];
        }
    }
    __syncthreads();
    if (wave==0 && lane<16){
        float S=0, Q=0, M=-3.0e38f;
        #pragma unroll
        for (int w=0;w<4;++w){
            S += sbuf[0][w][lane];
            Q += sbuf[1][w][lane];
            M  = fmaxf(M, sbuf[2][w][lane]);
        }
        float mean = S * (1.0f/NM);
        float var  = Q * (1.0f/NM) - mean*mean;
        float rstd = rsqrtf(fmaxf(var,0.0f) + 1e-5f);
        int row = n0 + lane;
        stats[row*2+0] = M;
        stats[row*2+1] = rstd * (1.0f/16.0f) * 1.4426950408889634f;
    }
}

// ---------------- K3: pass 2 — recompute S, softmax, PV, residual ----------------
// NEW structure: 4 waves share one 16-row q tile. Per 128-wide j-tile:
//   each wave computes S/P for its 32-j slice into a SHARED double-buffered
//   LDS P tile (1 barrier/iter), then computes O for its OWN 64-col co-slice
//   using the full 128-j P row. Accumulator: 4 f32x4 (16 regs) instead of 64.
__global__ __launch_bounds__(256) void flash_kernel(
    const bf16* __restrict__ q, const bf16* __restrict__ k,
    const bf16* __restrict__ vt, const float* __restrict__ stats,
    const float* __restrict__ query, bf16* __restrict__ u)
{
    __shared__ __align__(16) bf16 plds[2][16][136];  // double-buffered shared P
    __shared__ float dbuf[4][16];
    const int wave = threadIdx.x>>6, lane = threadIdx.x&63;
    const int lr = lane&15, lg = lane>>4;
    const int n0 = blockIdx.x*16;
    const int b = n0 / NQ;
    const bf16* kb = k  + (size_t)b*NM*CD;
    const bf16* vb = vt + (size_t)b*CD*NM + (size_t)(wave*64)*NM;  // wave's co-slice

    bf16x8 qf[8];
    const bf16* qr = q + (size_t)(n0+lr)*CD + lg*8;
    #pragma unroll
    for (int ch=0; ch<8; ++ch) qf[ch] = *(const bf16x8*)(qr + ch*32);

    float mxr[4], a2r[4];
    #pragma unroll
    for (int r=0;r<4;++r){
        int row = n0 + 4*lg + r;
        mxr[r] = stats[row*2+0];
        a2r[r] = stats[row*2+1];
    }

    f32x4 oacc[4];
    #pragma unroll
    for (int t=0;t<4;++t) oacc[t]=(f32x4){0,0,0,0};
    float denom[4]={0,0,0,0};

    for (int jt=0; jt<NM/128; ++jt){
        const int j0 = jt*128 + wave*32;
        const int buf = jt&1;
        // ---- QK for this wave's 32-j slice: 4 independent chains ----
        f32x4 a00=(f32x4){0,0,0,0}, a01=(f32x4){0,0,0,0};
        f32x4 a10=(f32x4){0,0,0,0}, a11=(f32x4){0,0,0,0};
        const bf16* kr0 = kb + (size_t)(j0+lr)*CD + lg*8;
        const bf16* kr1 = kr0 + 16*CD;
        #pragma unroll
        for (int ch=0; ch<4; ++ch){
            a00 = MFMA(qf[ch],   *(const bf16x8*)(kr0 + ch*32),     a00);
            a10 = MFMA(qf[ch],   *(const bf16x8*)(kr1 + ch*32),     a10);
            a01 = MFMA(qf[ch+4], *(const bf16x8*)(kr0 + (ch+4)*32), a01);
            a11 = MFMA(qf[ch+4], *(const bf16x8*)(kr1 + (ch+4)*32), a11);
        }
        #pragma unroll
        for (int r=0;r<4;++r){
            float p0 = exp2f(((a00[r]+a01[r])-mxr[r])*a2r[r]);
            float p1 = exp2f(((a10[r]+a11[r])-mxr[r])*a2r[r]);
            denom[r] += p0 + p1;
            plds[buf][4*lg+r][wave*32+lr]    = (bf16)p0;
            plds[buf][4*lg+r][wave*32+16+lr] = (bf16)p1;
        }
        __syncthreads();   // P tile complete; dbl-buffer makes 1 barrier/iter safe
        // ---- PV: full 128-j P rows x wave's 64 co columns ----
        bf16x8 pf[4];
        #pragma unroll
        for (int ks=0; ks<4; ++ks)
            pf[ks] = *(const bf16x8*)&plds[buf][lr][ks*32+lg*8];
        #pragma unroll
        for (int t=0;t<4;++t){
            const bf16* vr = vb + (size_t)(t*16+lr)*NM + jt*128 + lg*8;
            #pragma unroll
            for (int ks=0; ks<4; ++ks)
                oacc[t] = MFMA(pf[ks], *(const bf16x8*)(vr + ks*32), oacc[t]);
        }
    }

    // denom: partial over this wave's j subset -> reduce over lr lanes
    #pragma unroll
    for (int off=1; off<16; off<<=1){
        #pragma unroll
        for (int r=0;r<4;++r) denom[r] += __shfl_xor(denom[r], off);
    }
    if (lr==0){
        #pragma unroll
        for (int r=0;r<4;++r) dbuf[wave][4*lg+r] = denom[r];
    }
    __syncthreads();
    float dall[4];
    #pragma unroll
    for (int r=0;r<4;++r){
        int i = 4*lg + r;
        dall[r] = 1.0f / (dbuf[0][i] + dbuf[1][i] + dbuf[2][i] + dbuf[3][i]);
    }
    // u = query + O/denom  (wave owns cols [wave*64, wave*64+64))
    #pragma unroll
    for (int t=0;t<4;++t){
        #pragma unroll
        for (int r=0;r<4;++r){
            int row = n0 + 4*lg + r;
            int c = wave*64 + t*16 + lr;
            float val = query[(size_t)row*CD + c] + oacc[t][r]*dall[r];
            u[(size_t)row*CD + c] = (bf16)val;
        }
    }
}

// ---------------- K4: final projection  out = u @ Wm^T + bm  (fp32 out) ----------------
// GRID MUST BE 512 (blockIdx.x = rowblk*2 + cohalf).
__global__ __launch_bounds__(256) void final_kernel(
    const bf16* __restrict__ U, const bf16* __restrict__ W,
    const float* __restrict__ bias, float* __restrict__ out)
{
    const int wave = threadIdx.x>>6, lane = threadIdx.x&63;
    const int lr = lane&15, lg = lane>>4;
    const int n0 = (blockIdx.x>>1)*64 + wave*16;
    const int co0 = (blockIdx.x&1)*128;

    bf16x8 uf[8];
    const bf16* ur = U + (size_t)(n0+lr)*CD + lg*8;
    #pragma unroll
    for (int ch=0; ch<8; ++ch) uf[ch] = *(const bf16x8*)(ur + ch*32);

    f32x4 acc[8];
    #pragma unroll
    for (int t=0;t<8;++t) acc[t]=(f32x4){0,0,0,0};

    #pragma unroll
    for (int t=0;t<8;++t){
        const bf16* wr = W + (size_t)(co0+t*16+lr)*CD + lg*8;
        #pragma unroll
        for (int ch=0; ch<8; ++ch)
            acc[t] = MFMA(*(const bf16x8*)(wr+ch*32), uf[ch], acc[t]);
    }
    const int n = n0 + lr;
    #pragma unroll
    for (int t=0;t<8;++t){
        int co = co0 + t*16 + 4*lg;
        f32x4 o;
        #pragma unroll
        for (int r=0;r<4;++r) o[r] = acc[t][r] + bias[co+r];
        *(f32x4*)(out + (size_t)n*CD + co) = o;
    }
}

extern "C" void kernel_launch(void* const* d_in, const int* in_sizes, int n_in,
                              void* d_out, int out_size, void* d_ws, size_t ws_size,
                              hipStream_t stream)
{
    const float* query = (const float*)d_in[0];
    const float* key_  = (const float*)d_in[1];
    const float* value = (const float*)d_in[2];
    const float* Wq = (const float*)d_in[3];
    const float* bq = (const float*)d_in[4];
    const float* Wk = (const float*)d_in[5];
    const float* bk = (const float*)d_in[6];
    const float* Wv = (const float*)d_in[7];
    const float* bv = (const float*)d_in[8];
    const float* Wm = (const float*)d_in[9];
    const float* bm = (const float*)d_in[10];
    float* out = (float*)d_out;

    bf16* wsb = (bf16*)d_ws;
    bf16* wqb = wsb;
    bf16* wkb = wqb + 65536;
    bf16* wvb = wkb + 65536;
    bf16* wmb = wvb + 65536;
    bf16* qbuf  = wsb + 4*65536;
    bf16* kbuf  = qbuf  + (size_t)NTOT*CD;
    bf16* vtbuf = kbuf  + (size_t)NTOT*CD;
    bf16* ubuf  = vtbuf + (size_t)NTOT*CD;
    float* statsbuf = (float*)(ubuf + (size_t)NTOT*CD);

    cvt_w_kernel<<<64,256,0,stream>>>(Wq, Wk, Wv, Wm, wsb);
    proj_kernel<0><<<512,256,0,stream>>>(query, wqb, bq, qbuf);
    proj_kernel<0><<<512,256,0,stream>>>(key_,  wkb, bk, kbuf);
    proj_kernel<1><<<512,256,0,stream>>>(value, wvb, bv, vtbuf);
    stats_kernel<<<1024,256,0,stream>>>(qbuf, kbuf, statsbuf);
    flash_kernel<<<1024,256,0,stream>>>(qbuf, kbuf, vtbuf, statsbuf, query, ubuf);
    final_kernel<<<512,256,0,stream>>>(ubuf, wmb, bm, out);   // grid 512 — NOT 1024 (R2-R4 fault)
}

// Round 8
// 382.639 us; speedup vs baseline: 2.7132x; 2.2609x over previous
//
#include <hip/hip_runtime.h>
#include <hip/hip_bf16.h>
#include <cmath>

#define CD 256
#define NQ 4096
#define NM 4096
#define NB 4
#define NTOT (NB*NQ)

typedef __bf16 bf16;
typedef __attribute__((ext_vector_type(8))) __bf16 bf16x8;
typedef __attribute__((ext_vector_type(4))) __bf16 bf16x4;
typedef __attribute__((ext_vector_type(4))) float f32x4;

#define MFMA(a,b,c) __builtin_amdgcn_mfma_f32_16x16x32_bf16(a,b,c,0,0,0)

// ---------------- K0: convert the four weight matrices to bf16 ----------------
__global__ __launch_bounds__(256) void cvt_w_kernel(
    const float* __restrict__ wq, const float* __restrict__ wk,
    const float* __restrict__ wv, const float* __restrict__ wm,
    bf16* __restrict__ out)
{
    int i = (blockIdx.x*256 + threadIdx.x)*4;
    const float* srcs[4] = {wq, wk, wv, wm};
    #pragma unroll
    for (int m=0;m<4;++m){
        f32x4 v = *(const f32x4*)(srcs[m]+i);
        bf16x4 o;
        #pragma unroll
        for (int e=0;e<4;++e) o[e] = (bf16)v[e];
        *(bf16x4*)(out + m*65536 + i) = o;
    }
}

// ---------------- K1: projection out = X @ W^T + b (bf16 out). GRID 1024 ----------------
// blockIdx = rowblk*4 + coq. Each wave: 16 rows x 64 cols.
template<int MODE>
__global__ __launch_bounds__(256) void proj_kernel(
    const float* __restrict__ X, const bf16* __restrict__ W,
    const float* __restrict__ bias, bf16* __restrict__ out)
{
    const int wave = threadIdx.x>>6, lane = threadIdx.x&63;
    const int lr = lane&15, lg = lane>>4;
    const int n0 = (blockIdx.x>>2)*64 + wave*16;
    const int co0 = (blockIdx.x&3)*64;

    bf16x8 xf[8];
    {
        const float* xr = X + (size_t)(n0+lr)*CD + lg*8;
        #pragma unroll
        for (int ch=0; ch<8; ++ch){
            f32x4 a = *(const f32x4*)(xr + ch*32);
            f32x4 b = *(const f32x4*)(xr + ch*32 + 4);
            bf16x8 t;
            #pragma unroll
            for (int e=0;e<4;++e){ t[e]=(bf16)a[e]; t[4+e]=(bf16)b[e]; }
            xf[ch]=t;
        }
    }
    f32x4 acc[4];
    #pragma unroll
    for (int t=0;t<4;++t) acc[t]=(f32x4){0,0,0,0};

    #pragma unroll
    for (int t=0;t<4;++t){
        const bf16* wr = W + (size_t)(co0+t*16+lr)*CD + lg*8;
        #pragma unroll
        for (int ch=0; ch<8; ++ch){
            bf16x8 wf = *(const bf16x8*)(wr + ch*32);
            if (MODE==0) acc[t] = MFMA(wf, xf[ch], acc[t]);   // D[co, n]
            else         acc[t] = MFMA(xf[ch], wf, acc[t]);   // D[n, co]
        }
    }

    if (MODE==0){
        const int n = n0 + lr;
        #pragma unroll
        for (int t=0;t<4;++t){
            int co = co0 + t*16 + 4*lg;
            bf16x4 o;
            #pragma unroll
            for (int r=0;r<4;++r) o[r] = (bf16)(acc[t][r] + bias[co+r]);
            *(bf16x4*)(out + (size_t)n*CD + co) = o;
        }
    } else {
        const int b = n0 / NM;
        const int m0 = (n0 % NM) + 4*lg;
        #pragma unroll
        for (int t=0;t<4;++t){
            int co = co0 + t*16 + lr;
            float bb = bias[co];
            bf16x4 o;
            #pragma unroll
            for (int r=0;r<4;++r) o[r] = (bf16)(acc[t][r] + bb);
            *(bf16x4*)(out + (size_t)b*CD*NM + (size_t)co*NM + m0) = o;
        }
    }
}

// ---------------- K2: stats pass — Q-tile 64, K staged in LDS, j-split 4. GRID 1024 ----------------
// blockIdx = qt*4 + slice. Wave w owns rows [n0+16w, n0+16w+16), full j-slice.
// Writes partials spart[row*4+slice][3] = {sum, ssq, max}.
__global__ __launch_bounds__(256) void stats_kernel(
    const bf16* __restrict__ q, const bf16* __restrict__ k,
    float* __restrict__ spart)
{
    __shared__ __align__(16) bf16 K_lds[32][264];   // 32 j-rows x 256 c, +16B pad
    const int wave = threadIdx.x>>6, lane = threadIdx.x&63;
    const int lr = lane&15, lg = lane>>4;
    const int qt = blockIdx.x>>2, slice = blockIdx.x&3;
    const int n0 = qt*64;
    const int b = n0 / NQ;
    const bf16* kb = k + (size_t)b*NM*CD;
    const int row16 = n0 + wave*16;

    bf16x8 qf[8];
    const bf16* qr = q + (size_t)(row16+lr)*CD + lg*8;
    #pragma unroll
    for (int ch=0; ch<8; ++ch) qf[ch] = *(const bf16x8*)(qr + ch*32);

    float sum[4]={0,0,0,0}, ssq[4]={0,0,0,0}, mx[4];
    #pragma unroll
    for (int r=0;r<4;++r) mx[r] = -3.0e38f;

    const int jbeg = slice*(NM/4);
    for (int it=0; it<(NM/4)/32; ++it){
        const int j0 = jbeg + it*32;
        // stage K tile (reg-staged; 4 x 16B per thread)
        #pragma unroll
        for (int kk=0;kk<4;++kk){
            int id = threadIdx.x + kk*256;
            int r = id>>5, cb = id&31;
            bf16x8 v = *(const bf16x8*)(kb + (size_t)(j0+r)*CD + cb*8);
            *(bf16x8*)&K_lds[r][cb*8] = v;
        }
        __syncthreads();
        f32x4 s0=(f32x4){0,0,0,0}, s1=(f32x4){0,0,0,0};
        #pragma unroll
        for (int ch=0; ch<8; ++ch){
            s0 = MFMA(qf[ch], *(const bf16x8*)&K_lds[lr][lg*8+ch*32], s0);
            s1 = MFMA(qf[ch], *(const bf16x8*)&K_lds[16+lr][lg*8+ch*32], s1);
        }
        __syncthreads();
        #pragma unroll
        for (int r=0;r<4;++r){
            float a = s0[r], c = s1[r];
            sum[r] += a + c;
            ssq[r] = fmaf(a,a,ssq[r]); ssq[r] = fmaf(c,c,ssq[r]);
            mx[r] = fmaxf(mx[r], fmaxf(a, c));
        }
    }
    #pragma unroll
    for (int off=1; off<16; off<<=1){
        #pragma unroll
        for (int r=0;r<4;++r){
            sum[r] += __shfl_xor(sum[r], off);
            ssq[r] += __shfl_xor(ssq[r], off);
            mx[r]  = fmaxf(mx[r], __shfl_xor(mx[r], off));
        }
    }
    if (lr==0){
        #pragma unroll
        for (int r=0;r<4;++r){
            int row = row16 + 4*lg + r;
            size_t idx = ((size_t)row*4 + slice)*3;
            spart[idx+0] = sum[r];
            spart[idx+1] = ssq[r];
            spart[idx+2] = mx[r];
        }
    }
}

// ---------------- K2b: finalize stats. GRID 64 ----------------
__global__ __launch_bounds__(256) void statsfin_kernel(
    const float* __restrict__ spart, float* __restrict__ stats)
{
    int row = blockIdx.x*256 + threadIdx.x;
    float S=0, Q=0, M=-3.0e38f;
    #pragma unroll
    for (int s=0;s<4;++s){
        size_t idx = ((size_t)row*4 + s)*3;
        S += spart[idx+0];
        Q += spart[idx+1];
        M  = fmaxf(M, spart[idx+2]);
    }
    float mean = S * (1.0f/NM);
    float var  = Q * (1.0f/NM) - mean*mean;
    float rstd = rsqrtf(fmaxf(var,0.0f) + 1e-5f);
    stats[row*2+0] = M;
    stats[row*2+1] = rstd * (1.0f/16.0f) * 1.4426950408889634f;
}

// ---------------- K3: flash pass 2 — Q-tile 64, K-LDS, co-split PV, j-split 4. GRID 1024 ----------------
// blockIdx = qt*4 + slice. Wave w: QK for rows [16w,16w+16); PV for co [64w,64w+64).
// Emits bf16 partial O + f32 partial denom per slice.
__global__ __launch_bounds__(256) void flash_kernel(
    const bf16* __restrict__ q, const bf16* __restrict__ k,
    const bf16* __restrict__ vt, const float* __restrict__ stats,
    bf16* __restrict__ opart, float* __restrict__ dpart)
{
    __shared__ __align__(16) bf16 K_lds[32][264];
    __shared__ __align__(16) bf16 P_lds[64][40];
    const int wave = threadIdx.x>>6, lane = threadIdx.x&63;
    const int lr = lane&15, lg = lane>>4;
    const int qt = blockIdx.x>>2, slice = blockIdx.x&3;
    const int n0 = qt*64;
    const int b = n0 / NQ;
    const bf16* kb = k  + (size_t)b*NM*CD;
    const bf16* vb = vt + (size_t)b*CD*NM + (size_t)(wave*64)*NM;  // wave's co-slice
    const int row16 = n0 + wave*16;

    bf16x8 qf[8];
    const bf16* qr = q + (size_t)(row16+lr)*CD + lg*8;
    #pragma unroll
    for (int ch=0; ch<8; ++ch) qf[ch] = *(const bf16x8*)(qr + ch*32);

    float mxr[4], a2r[4];
    #pragma unroll
    for (int r=0;r<4;++r){
        int row = row16 + 4*lg + r;
        mxr[r] = stats[row*2+0];
        a2r[r] = stats[row*2+1];
    }

    f32x4 oacc[4][4];   // [row-tile rt][co-tile ct]
    #pragma unroll
    for (int rt=0;rt<4;++rt)
        #pragma unroll
        for (int ct=0;ct<4;++ct) oacc[rt][ct]=(f32x4){0,0,0,0};
    float denom[4]={0,0,0,0};

    const int jbeg = slice*(NM/4);
    for (int it=0; it<(NM/4)/32; ++it){
        const int j0 = jbeg + it*32;
        // ---- stage K tile ----
        #pragma unroll
        for (int kk=0;kk<4;++kk){
            int id = threadIdx.x + kk*256;
            int r = id>>5, cb = id&31;
            bf16x8 v = *(const bf16x8*)(kb + (size_t)(j0+r)*CD + cb*8);
            *(bf16x8*)&K_lds[r][cb*8] = v;
        }
        __syncthreads();
        // ---- QK for this wave's 16 rows x 32 j ----
        f32x4 s0=(f32x4){0,0,0,0}, s1=(f32x4){0,0,0,0};
        #pragma unroll
        for (int ch=0; ch<8; ++ch){
            s0 = MFMA(qf[ch], *(const bf16x8*)&K_lds[lr][lg*8+ch*32], s0);
            s1 = MFMA(qf[ch], *(const bf16x8*)&K_lds[16+lr][lg*8+ch*32], s1);
        }
        #pragma unroll
        for (int r=0;r<4;++r){
            float p0 = exp2f((s0[r]-mxr[r])*a2r[r]);
            float p1 = exp2f((s1[r]-mxr[r])*a2r[r]);
            denom[r] += p0 + p1;
            P_lds[wave*16+4*lg+r][lr]    = (bf16)p0;
            P_lds[wave*16+4*lg+r][16+lr] = (bf16)p1;
        }
        __syncthreads();   // P complete; K_lds reads done (safe to restage next iter)
        // ---- PV: all 64 rows x wave's 64 co, k=32 ----
        bf16x8 pf[4];
        #pragma unroll
        for (int rt=0;rt<4;++rt)
            pf[rt] = *(const bf16x8*)&P_lds[rt*16+lr][lg*8];
        #pragma unroll
        for (int ct=0;ct<4;++ct){
            bf16x8 vf = *(const bf16x8*)(vb + (size_t)(ct*16+lr)*NM + j0 + lg*8);
            #pragma unroll
            for (int rt=0;rt<4;++rt)
                oacc[rt][ct] = MFMA(pf[rt], vf, oacc[rt][ct]);
        }
    }

    // partial denom for this wave's rows
    #pragma unroll
    for (int off=1; off<16; off<<=1){
        #pragma unroll
        for (int r=0;r<4;++r) denom[r] += __shfl_xor(denom[r], off);
    }
    if (lr==0){
        #pragma unroll
        for (int r=0;r<4;++r)
            dpart[(size_t)slice*NTOT + row16 + 4*lg + r] = denom[r];
    }
    // partial O (bf16)
    #pragma unroll
    for (int rt=0;rt<4;++rt){
        #pragma unroll
        for (int ct=0;ct<4;++ct){
            #pragma unroll
            for (int r=0;r<4;++r){
                int row = n0 + rt*16 + 4*lg + r;
                int co  = wave*64 + ct*16 + lr;
                opart[((size_t)slice*NTOT + row)*CD + co] = (bf16)oacc[rt][ct][r];
            }
        }
    }
}

// ---------------- K3b: combine partials -> u = query + O/denom (bf16). GRID 2048 ----------------
__global__ __launch_bounds__(256) void combine_kernel(
    const bf16* __restrict__ opart, const float* __restrict__ dpart,
    const float* __restrict__ query, bf16* __restrict__ u)
{
    int gid = blockIdx.x*256 + threadIdx.x;       // 524288 threads
    int row = gid>>5, c0 = (gid&31)*8;
    float dsum = dpart[row] + dpart[NTOT+row] + dpart[2*NTOT+row] + dpart[3*(size_t)NTOT+row];
    float inv = 1.0f/dsum;
    float acc[8]={0,0,0,0,0,0,0,0};
    #pragma unroll
    for (int s=0;s<4;++s){
        bf16x8 o = *(const bf16x8*)&opart[((size_t)s*NTOT+row)*CD + c0];
        #pragma unroll
        for (int e=0;e<8;++e) acc[e] += (float)o[e];
    }
    f32x4 qa = *(const f32x4*)(query + (size_t)row*CD + c0);
    f32x4 qb = *(const f32x4*)(query + (size_t)row*CD + c0 + 4);
    bf16x8 out;
    #pragma unroll
    for (int e=0;e<4;++e){
        out[e]   = (bf16)(qa[e] + acc[e]*inv);
        out[4+e] = (bf16)(qb[e] + acc[4+e]*inv);
    }
    *(bf16x8*)&u[(size_t)row*CD + c0] = out;
}

// ---------------- K4: final projection out = u @ Wm^T + bm (fp32 out). GRID 1024 ----------------
__global__ __launch_bounds__(256) void final_kernel(
    const bf16* __restrict__ U, const bf16* __restrict__ W,
    const float* __restrict__ bias, float* __restrict__ out)
{
    const int wave = threadIdx.x>>6, lane = threadIdx.x&63;
    const int lr = lane&15, lg = lane>>4;
    const int n0 = (blockIdx.x>>2)*64 + wave*16;
    const int co0 = (blockIdx.x&3)*64;

    bf16x8 uf[8];
    const bf16* ur = U + (size_t)(n0+lr)*CD + lg*8;
    #pragma unroll
    for (int ch=0; ch<8; ++ch) uf[ch] = *(const bf16x8*)(ur + ch*32);

    f32x4 acc[4];
    #pragma unroll
    for (int t=0;t<4;++t) acc[t]=(f32x4){0,0,0,0};

    #pragma unroll
    for (int t=0;t<4;++t){
        const bf16* wr = W + (size_t)(co0+t*16+lr)*CD + lg*8;
        #pragma unroll
        for (int ch=0; ch<8; ++ch)
            acc[t] = MFMA(*(const bf16x8*)(wr+ch*32), uf[ch], acc[t]);
    }
    const int n = n0 + lr;
    #pragma unroll
    for (int t=0;t<4;++t){
        int co = co0 + t*16 + 4*lg;
        f32x4 o;
        #pragma unroll
        for (int r=0;r<4;++r) o[r] = acc[t][r] + bias[co+r];
        *(f32x4*)(out + (size_t)n*CD + co) = o;
    }
}

extern "C" void kernel_launch(void* const* d_in, const int* in_sizes, int n_in,
                              void* d_out, int out_size, void* d_ws, size_t ws_size,
                              hipStream_t stream)
{
    const float* query = (const float*)d_in[0];
    const float* key_  = (const float*)d_in[1];
    const float* value = (const float*)d_in[2];
    const float* Wq = (const float*)d_in[3];
    const float* bq = (const float*)d_in[4];
    const float* Wk = (const float*)d_in[5];
    const float* bk = (const float*)d_in[6];
    const float* Wv = (const float*)d_in[7];
    const float* bv = (const float*)d_in[8];
    const float* Wm = (const float*)d_in[9];
    const float* bm = (const float*)d_in[10];
    float* out = (float*)d_out;

    bf16* wsb = (bf16*)d_ws;
    bf16* wqb = wsb;                                   // 4 x 65536 bf16 weights
    bf16* wkb = wqb + 65536;
    bf16* wvb = wkb + 65536;
    bf16* wmb = wvb + 65536;
    bf16* qbuf  = wsb + 4*65536;                       // [NTOT][256] bf16
    bf16* kbuf  = qbuf  + (size_t)NTOT*CD;
    bf16* vtbuf = kbuf  + (size_t)NTOT*CD;             // [B][256][NM]
    bf16* ubuf  = vtbuf + (size_t)NTOT*CD;
    float* statsbuf = (float*)(ubuf + (size_t)NTOT*CD);            // [NTOT][2]
    float* spart    = statsbuf + (size_t)NTOT*2;                   // [NTOT][4][3]
    float* dpart    = spart + (size_t)NTOT*12;                     // [4][NTOT]
    bf16*  opart    = (bf16*)(dpart + (size_t)NTOT*4);             // [4][NTOT][256]

    cvt_w_kernel<<<64,256,0,stream>>>(Wq, Wk, Wv, Wm, wsb);
    proj_kernel<0><<<1024,256,0,stream>>>(query, wqb, bq, qbuf);   // grid 1024 (co-split 4)
    proj_kernel<0><<<1024,256,0,stream>>>(key_,  wkb, bk, kbuf);
    proj_kernel<1><<<1024,256,0,stream>>>(value, wvb, bv, vtbuf);
    stats_kernel<<<1024,256,0,stream>>>(qbuf, kbuf, spart);        // grid = 256 qt x 4 slices
    statsfin_kernel<<<64,256,0,stream>>>(spart, statsbuf);
    flash_kernel<<<1024,256,0,stream>>>(qbuf, kbuf, vtbuf, statsbuf, opart, dpart);
    combine_kernel<<<2048,256,0,stream>>>(opart, dpart, query, ubuf);
    final_kernel<<<1024,256,0,stream>>>(ubuf, wmb, bm, out);       // grid 1024 (co-split 4)
}